// Round 9
// baseline (325.728 us; speedup 1.0000x reference)
//
#include <hip/hip_runtime.h>
#include <hip/hip_fp16.h>

#define MDIM 8192   // B*S = 4*2048
#define NDIM 4096   // OUT
#define KDIM 4096   // IN

typedef unsigned short u16;
typedef __bf16 bf16x8 __attribute__((ext_vector_type(8)));
typedef float f32x4 __attribute__((ext_vector_type(4)));
typedef float f32x16 __attribute__((ext_vector_type(16)));

static __device__ __forceinline__ u16 f2bf(float f) {
  union { float f; unsigned u; } v; v.f = f;
  unsigned r = v.u + 0x7fffu + ((v.u >> 16) & 1u);  // round-to-nearest-even
  return (u16)(r >> 16);
}

// scales/zeros may arrive as fp16 (reference dtype) or promoted to fp32.
static __device__ __forceinline__ bool sz_is_f32(const void* sc) {
  unsigned w0 = ((const unsigned*)sc)[0];
  return ((w0 >> 16) & 0x7fffu) >= 0x3000u;
}
static __device__ __forceinline__ float load_sz(const void* p, int i, bool f32) {
  return f32 ? ((const float*)p)[i] : __half2float(((const __half*)p)[i]);
}

// ---------------- kernel 1: fused {x fp32->bf16 conv} + {dequant+LoRA W_eff} ----------------
#define CONVB 2048
#define WEFFB 512
__global__ void qlora_prep(const float4* __restrict__ x, ushort4* __restrict__ xb,
                           const int* __restrict__ qw, const void* __restrict__ sc,
                           const void* __restrict__ zr, const float* __restrict__ lA,
                           const float* __restrict__ lB, ushort2* __restrict__ weff) {
  if (blockIdx.x < CONVB) {
    unsigned base = blockIdx.x * 256u + threadIdx.x;
#pragma unroll
    for (int s = 0; s < 16; ++s) {
      unsigned i = base + (unsigned)s * (CONVB * 256u);
      float4 a = x[i];
      ushort4 o;
      o.x = f2bf(a.x); o.y = f2bf(a.y); o.z = f2bf(a.z); o.w = f2bf(a.w);
      xb[i] = o;
    }
  } else {
    __shared__ __align__(16) float lA_s[16][512];
    __shared__ float lB_s[64][16];
    __shared__ float s_s[64], z_s[64];
    const int bid = blockIdx.x - CONVB;        // 0..511
    const int t = threadIdx.x;
    const int o0 = (bid & 63) * 64;            // O-tile
    const int it0 = (bid >> 6) * 512;          // I-tile
    const bool f32 = sz_is_f32(sc);
#pragma unroll
    for (int s = 0; s < 8; ++s) {
      int idx = s * 256 + t;
      int r = idx >> 7, c4 = idx & 127;
      *(float4*)&lA_s[r][c4 * 4] = *(const float4*)(lA + (size_t)r * KDIM + it0 + c4 * 4);
    }
#pragma unroll
    for (int s = 0; s < 4; ++s) {
      int idx = s * 256 + t;
      int o = idx >> 4, r = idx & 15;
      lB_s[o][r] = lB[(o0 + o) * 16 + r] * 2.0f;   // SCALING = 32/16
    }
    if (t < 64) {
      s_s[t] = load_sz(sc, o0 + t, f32);
      z_s[t] = load_sz(zr, o0 + t, f32);
    }
    __syncthreads();
    float2 a2[16];
#pragma unroll
    for (int r = 0; r < 16; ++r) a2[r] = *(const float2*)&lA_s[r][2 * t];
    const size_t i2 = (size_t)(it0 / 2 + t);
    const int* qcol = qw + i2;
    ushort2* wcol = weff + i2;
#pragma unroll 4
    for (int o = 0; o < 64; ++o) {
      const int oo = o0 + o;
      int q = qcol[(size_t)oo * (KDIM / 2)];
      float acc0 = 0.f, acc1 = 0.f;
#pragma unroll
      for (int r = 0; r < 16; ++r) {
        float br = lB_s[o][r];
        acc0 += br * a2[r].x;
        acc1 += br * a2[r].y;
      }
      const float s = s_s[o], z = z_s[o];
      float w0 = (float)((q >> 4) & 15) * s + z + acc0;   // high nibble -> even col
      float w1 = (float)(q & 15) * s + z + acc1;          // low nibble -> odd col
      ushort2 pk; pk.x = f2bf(w0); pk.y = f2bf(w1);
      wcol[(size_t)oo * (KDIM / 2)] = pk;
    }
  }
}

// ---------------- kernel 2: 256x256 GEMM, r6 2-gate schedule + 32x32x16 MFMA ----------------
// C[M][N] = A[M][K] * B[N][K]^T. 8 waves (2Mx4N), wave-tile 128x64, BK=64,
// LDS 128KiB dbuf [256 rows][64 k] per matrix, granule ^= row&7 swizzle.
// Per K-tile: vmcnt(2)+bar (A0,B0,B1 arrived; A1 in flight) -> read A-qm0 + B,
// stage A0,B0(kt+1), MFMA qm0 (16x mfma_32x32x16), stage B1(kt+1),
// vmcnt(6)+bar (A1 arrived; kt+1 stays in flight) -> read A-qm1, stage A1,
// MFMA qm1. 2D XCD mapping: each XCD owns an 8x8 square of 256-tiles.
// 32x32 operand/C-D layouts proven end-to-end in round 7 (absmax 0.25).

#define STAGE(SB, BUFSEL, REGOFF, HALF, KT) do {                                   \
    const u16* _s0 = (SB) + (size_t)(HALF) * (128 * (size_t)KDIM) + (KT) * 64;     \
    u16* _d0 = lds + (BUFSEL) * 32768 + (REGOFF) + (HALF) * 8192 + wave * 1024;    \
    __builtin_amdgcn_global_load_lds(                                              \
        (const __attribute__((address_space(1))) void*)_s0,                        \
        (__attribute__((address_space(3))) void*)_d0, 16, 0, 0);                   \
    __builtin_amdgcn_global_load_lds(                                              \
        (const __attribute__((address_space(1))) void*)(_s0 + 8 * KDIM),           \
        (__attribute__((address_space(3))) void*)(_d0 + 512), 16, 0, 0);           \
  } while (0)

#define SBAR0 __builtin_amdgcn_sched_barrier(0)

__global__ __launch_bounds__(512, 2) void qlora_gemm32(const u16* __restrict__ A,
                                                       const u16* __restrict__ B,
                                                       float* __restrict__ C) {
  __shared__ __align__(16) u16 lds[65536];  // 128 KiB: buf{0,1} x (A 32KB + B 32KB)

  const int t = threadIdx.x;
  const int lane = t & 63;
  const int wave = t >> 6;          // 0..7
  const int wr = wave >> 2;         // 0..1  (M)
  const int wc = wave & 3;          // 0..3  (N)
  const int l31 = lane & 31;
  const int l5 = lane >> 5;         // 0..1
  const int gx = l31 & 7;           // row&7 component of the read-granule XOR

  // 2D XCD mapping: XCD = flat&7 owns an 8x8 square of 256-tiles (L2-resident)
  const int flat = blockIdx.x;
  const int xcd = flat & 7;
  const int idx = flat >> 3;                       // 0..63
  const int brow = ((xcd & 3) * 8 + (idx & 7)) * 256;
  const int bcol = ((xcd >> 2) * 8 + (idx >> 3)) * 256;

  // per-thread LDS read base offsets (u16 units; granule XOR folded per-read)
  const int aBase = (wr * 64 + l31) * 64;            // + qm*8192 + mf2*2048
  const int bBase = 16384 + (wc * 64 + l31) * 64;    // + nf2*2048

  // per-thread pre-swizzled global staging bases:
  // row = wave*16 + L*8 + (lane>>3), granule = (lane&7) ^ ((lane>>3)&7)
  const int srow = wave * 16 + (lane >> 3);
  const int sg = ((lane & 7) ^ ((lane >> 3) & 7)) * 8;
  const u16* aS = A + (size_t)(brow + srow) * KDIM + sg;
  const u16* bS = B + (size_t)(bcol + srow) * KDIM + sg;

  f32x16 acc0[2][2] = {};   // qm=0: [mf2][nf2]
  f32x16 acc1[2][2] = {};   // qm=1

  // prologue: stage kt0 in issue-order [A0, B0, B1, A1] -> buf0 (8 loads)
  STAGE(aS, 0, 0, 0, 0);
  STAGE(bS, 0, 16384, 0, 0);
  STAGE(bS, 0, 16384, 1, 0);
  STAGE(aS, 0, 0, 1, 0);

#pragma unroll 1
  for (int it = 0; it < KDIM / 64; ++it) {
    const int buf = it & 1;
    const int nbuf = buf ^ 1;
    const int nxt = (it + 1) & 63;
    const int abase = buf * 32768;

    // ---- gate 1: A0,B0,B1(kt) arrived (vmcnt(2) leaves A1 in flight) ----
    asm volatile("s_waitcnt vmcnt(2)" ::: "memory");
    SBAR0;
    __builtin_amdgcn_s_barrier();
    SBAR0;

    // reads: A qm0 (2 mf2 x 4 ks) + B (2 nf2 x 4 ks); granule = (2ks+l5)^gx
    bf16x8 a0[2][4], b0[2][4];
#pragma unroll
    for (int mf2 = 0; mf2 < 2; ++mf2)
#pragma unroll
      for (int ks = 0; ks < 4; ++ks)
        a0[mf2][ks] = *(const bf16x8*)(lds + (abase + aBase + mf2 * 2048 +
                                              (((2 * ks + l5) ^ gx) * 8)));
#pragma unroll
    for (int nf2 = 0; nf2 < 2; ++nf2)
#pragma unroll
      for (int ks = 0; ks < 4; ++ks)
        b0[nf2][ks] = *(const bf16x8*)(lds + (abase + bBase + nf2 * 2048 +
                                              (((2 * ks + l5) ^ gx) * 8)));
    SBAR0;
    STAGE(aS, nbuf, 0, 0, nxt);        // A0(kt+1)
    STAGE(bS, nbuf, 16384, 0, nxt);    // B0(kt+1)
    SBAR0;

    // MFMA cluster qm0: 16 x 32x32x16
    __builtin_amdgcn_s_setprio(1);
#pragma unroll
    for (int mf2 = 0; mf2 < 2; ++mf2)
#pragma unroll
      for (int nf2 = 0; nf2 < 2; ++nf2)
#pragma unroll
        for (int ks = 0; ks < 4; ++ks)
          acc0[mf2][nf2] = __builtin_amdgcn_mfma_f32_32x32x16_bf16(
              a0[mf2][ks], b0[nf2][ks], acc0[mf2][nf2], 0, 0, 0);
    __builtin_amdgcn_s_setprio(0);
    SBAR0;
    STAGE(bS, nbuf, 16384, 1, nxt);    // B1(kt+1)
    SBAR0;

    // ---- gate 2: A1(kt) arrived (vmcnt(6) keeps kt+1's A0,B0,B1 in flight) ----
    asm volatile("s_waitcnt vmcnt(6)" ::: "memory");
    SBAR0;
    __builtin_amdgcn_s_barrier();
    SBAR0;

    // reads: A qm1
    bf16x8 a1[2][4];
#pragma unroll
    for (int mf2 = 0; mf2 < 2; ++mf2)
#pragma unroll
      for (int ks = 0; ks < 4; ++ks)
        a1[mf2][ks] = *(const bf16x8*)(lds + (abase + 8192 + aBase + mf2 * 2048 +
                                              (((2 * ks + l5) ^ gx) * 8)));
    STAGE(aS, nbuf, 0, 1, nxt);        // A1(kt+1)
    SBAR0;

    // MFMA cluster qm1
    __builtin_amdgcn_s_setprio(1);
#pragma unroll
    for (int mf2 = 0; mf2 < 2; ++mf2)
#pragma unroll
      for (int nf2 = 0; nf2 < 2; ++nf2)
#pragma unroll
        for (int ks = 0; ks < 4; ++ks)
          acc1[mf2][nf2] = __builtin_amdgcn_mfma_f32_32x32x16_bf16(
              a1[mf2][ks], b0[nf2][ks], acc1[mf2][nf2], 0, 0, 0);
    __builtin_amdgcn_s_setprio(0);
    SBAR0;
  }

  asm volatile("s_waitcnt vmcnt(0) lgkmcnt(0)" ::: "memory");

  // epilogue: 32x32 C/D layout: col = lane&31, row = (r&3) + 8*(r>>2) + 4*(lane>>5)
  float* Cb = C + (size_t)brow * NDIM + bcol;
#pragma unroll
  for (int mf2 = 0; mf2 < 2; ++mf2)
#pragma unroll
    for (int nf2 = 0; nf2 < 2; ++nf2) {
      {
        f32x16 v = acc0[mf2][nf2];
        const int r0 = wr * 64 + mf2 * 32;
        const int c0 = wc * 64 + nf2 * 32 + l31;
#pragma unroll
        for (int r = 0; r < 16; ++r) {
          int row = r0 + (r & 3) + 8 * (r >> 2) + 4 * l5;
          Cb[(size_t)row * NDIM + c0] = v[r];
        }
      }
      {
        f32x16 v = acc1[mf2][nf2];
        const int r0 = 128 + wr * 64 + mf2 * 32;
        const int c0 = wc * 64 + nf2 * 32 + l31;
#pragma unroll
        for (int r = 0; r < 16; ++r) {
          int row = r0 + (r & 3) + 8 * (r >> 2) + 4 * l5;
          Cb[(size_t)row * NDIM + c0] = v[r];
        }
      }
    }
}

// ---------------- fallback: fp32 tiled GEMM with on-the-fly dequant (no ws) ----------------
__global__ void qlora_fallback(const float* __restrict__ X, const int* __restrict__ qw,
                               const void* __restrict__ sc, const void* __restrict__ zr,
                               const float* __restrict__ lA, const float* __restrict__ lB,
                               float* __restrict__ C) {
  __shared__ float Xs[32][65];
  __shared__ float Ws[32][65];
  const int t = threadIdx.x;
  const bool f32 = sz_is_f32(sc);
  const int brow = blockIdx.x * 64, bcol = blockIdx.y * 64;
  const int tr = t >> 4, tc = t & 15;
  float acc[4][4] = {};
  for (int k0 = 0; k0 < KDIM; k0 += 32) {
    __syncthreads();
    {
      int row = t >> 2;
      int kk0 = (t & 3) * 8;
      const float* src = X + (size_t)(brow + row) * KDIM + k0 + kk0;
#pragma unroll
      for (int u = 0; u < 8; ++u) Xs[kk0 + u][row] = src[u];
    }
    {
      int o = t >> 2;
      int kk0 = (t & 3) * 8;
      int oo = bcol + o;
      float s = load_sz(sc, oo, f32), z = load_sz(zr, oo, f32);
      const int* qrow = qw + (size_t)oo * (KDIM / 2) + (k0 + kk0) / 2;
#pragma unroll
      for (int u = 0; u < 4; ++u) {
        int q = qrow[u];
        int kk = kk0 + u * 2;
        float l0 = 0.f, l1 = 0.f;
#pragma unroll
        for (int r = 0; r < 16; ++r) {
          float br = lB[oo * 16 + r] * 2.0f;
          l0 += br * lA[(size_t)r * KDIM + k0 + kk];
          l1 += br * lA[(size_t)r * KDIM + k0 + kk + 1];
        }
        Ws[kk][o] = (float)((q >> 4) & 15) * s + z + l0;
        Ws[kk + 1][o] = (float)(q & 15) * s + z + l1;
      }
    }
    __syncthreads();
#pragma unroll
    for (int k = 0; k < 32; ++k) {
      float xv[4], wv[4];
#pragma unroll
      for (int i = 0; i < 4; ++i) xv[i] = Xs[k][tr * 4 + i];
#pragma unroll
      for (int j = 0; j < 4; ++j) wv[j] = Ws[k][tc * 4 + j];
#pragma unroll
      for (int i = 0; i < 4; ++i)
#pragma unroll
        for (int j = 0; j < 4; ++j) acc[i][j] += xv[i] * wv[j];
    }
  }
#pragma unroll
  for (int i = 0; i < 4; ++i)
#pragma unroll
    for (int j = 0; j < 4; ++j)
      C[(size_t)(brow + tr * 4 + i) * NDIM + bcol + tc * 4 + j] = acc[i][j];
}

extern "C" void kernel_launch(void* const* d_in, const int* in_sizes, int n_in,
                              void* d_out, int out_size, void* d_ws, size_t ws_size,
                              hipStream_t stream) {
  const float* x = (const float*)d_in[0];
  const int* qw = (const int*)d_in[1];
  const void* sc = d_in[2];
  const void* zr = d_in[3];
  const float* lA = (const float*)d_in[4];
  const float* lB = (const float*)d_in[5];
  float* out = (float*)d_out;

  const size_t xb_bytes = (size_t)MDIM * KDIM * 2;
  const size_t weff_bytes = (size_t)NDIM * KDIM * 2;
  if (ws_size >= xb_bytes + weff_bytes) {
    u16* xb = (u16*)d_ws;
    u16* weff = xb + (size_t)MDIM * KDIM;
    qlora_prep<<<CONVB + WEFFB, 256, 0, stream>>>((const float4*)x, (ushort4*)xb,
                                                  qw, sc, zr, lA, lB, (ushort2*)weff);
    dim3 grid((MDIM / 256) * (NDIM / 256));  // 512 blocks
    qlora_gemm32<<<grid, 512, 0, stream>>>(xb, weff, out);
  } else {
    dim3 grid(MDIM / 64, NDIM / 64);
    qlora_fallback<<<grid, 256, 0, stream>>>(x, qw, sc, zr, lA, lB, out);
  }
}

// Round 10
// 288.388 us; speedup vs baseline: 1.1295x; 1.1295x over previous
//
#include <hip/hip_runtime.h>
#include <hip/hip_fp16.h>

#define MDIM 8192   // B*S = 4*2048
#define NDIM 4096   // OUT
#define KDIM 4096   // IN

typedef unsigned short u16;
typedef __bf16 bf16x8 __attribute__((ext_vector_type(8)));
typedef float f32x4 __attribute__((ext_vector_type(4)));

static __device__ __forceinline__ u16 f2bf(float f) {
  union { float f; unsigned u; } v; v.f = f;
  unsigned r = v.u + 0x7fffu + ((v.u >> 16) & 1u);  // round-to-nearest-even
  return (u16)(r >> 16);
}

// scales/zeros may arrive as fp16 (reference dtype) or promoted to fp32.
static __device__ __forceinline__ bool sz_is_f32(const void* sc) {
  unsigned w0 = ((const unsigned*)sc)[0];
  return ((w0 >> 16) & 0x7fffu) >= 0x3000u;
}
static __device__ __forceinline__ float load_sz(const void* p, int i, bool f32) {
  return f32 ? ((const float*)p)[i] : __half2float(((const __half*)p)[i]);
}

// ---------------- kernel 1: fused {x fp32->bf16 conv} + {dequant+LoRA W_eff} ----------------
#define CONVB 2048
#define WEFFB 512
__global__ void qlora_prep(const float4* __restrict__ x, ushort4* __restrict__ xb,
                           const int* __restrict__ qw, const void* __restrict__ sc,
                           const void* __restrict__ zr, const float* __restrict__ lA,
                           const float* __restrict__ lB, ushort2* __restrict__ weff) {
  if (blockIdx.x < CONVB) {
    unsigned base = blockIdx.x * 256u + threadIdx.x;
#pragma unroll
    for (int s = 0; s < 16; ++s) {
      unsigned i = base + (unsigned)s * (CONVB * 256u);
      float4 a = x[i];
      ushort4 o;
      o.x = f2bf(a.x); o.y = f2bf(a.y); o.z = f2bf(a.z); o.w = f2bf(a.w);
      xb[i] = o;
    }
  } else {
    __shared__ __align__(16) float lA_s[16][512];
    __shared__ float lB_s[64][16];
    __shared__ float s_s[64], z_s[64];
    const int bid = blockIdx.x - CONVB;        // 0..511
    const int t = threadIdx.x;
    const int o0 = (bid & 63) * 64;            // O-tile
    const int it0 = (bid >> 6) * 512;          // I-tile
    const bool f32 = sz_is_f32(sc);
#pragma unroll
    for (int s = 0; s < 8; ++s) {
      int idx = s * 256 + t;
      int r = idx >> 7, c4 = idx & 127;
      *(float4*)&lA_s[r][c4 * 4] = *(const float4*)(lA + (size_t)r * KDIM + it0 + c4 * 4);
    }
#pragma unroll
    for (int s = 0; s < 4; ++s) {
      int idx = s * 256 + t;
      int o = idx >> 4, r = idx & 15;
      lB_s[o][r] = lB[(o0 + o) * 16 + r] * 2.0f;   // SCALING = 32/16
    }
    if (t < 64) {
      s_s[t] = load_sz(sc, o0 + t, f32);
      z_s[t] = load_sz(zr, o0 + t, f32);
    }
    __syncthreads();
    float2 a2[16];
#pragma unroll
    for (int r = 0; r < 16; ++r) a2[r] = *(const float2*)&lA_s[r][2 * t];
    const size_t i2 = (size_t)(it0 / 2 + t);
    const int* qcol = qw + i2;
    ushort2* wcol = weff + i2;
#pragma unroll 4
    for (int o = 0; o < 64; ++o) {
      const int oo = o0 + o;
      int q = qcol[(size_t)oo * (KDIM / 2)];
      float acc0 = 0.f, acc1 = 0.f;
#pragma unroll
      for (int r = 0; r < 16; ++r) {
        float br = lB_s[o][r];
        acc0 += br * a2[r].x;
        acc1 += br * a2[r].y;
      }
      const float s = s_s[o], z = z_s[o];
      float w0 = (float)((q >> 4) & 15) * s + z + acc0;   // high nibble -> even col
      float w1 = (float)(q & 15) * s + z + acc1;          // low nibble -> odd col
      ushort2 pk; pk.x = f2bf(w0); pk.y = f2bf(w1);
      wcol[(size_t)oo * (KDIM / 2)] = pk;
    }
  }
}

// ---------------- kernel 2: 256x256 staggered 8-phase bf16 MFMA GEMM ----------------
// C[M][N] = A[M][K] * B[N][K]^T. 8 waves (2Mx4N), BK=64, LDS 128KiB dbuf,
// XOR-swizzle (granule ^= row&7), 16x16x32 MFMA (conflict-free pattern).
// 8 phases / 2 K-tiles: one half-tile stage per phase in fixed order
// [B1(o),A1(o),A0(e'),B0(e'),B1(e'),A1(e'),A0(o'),B0(o')]; gates vmcnt(6/8/6/8)
// at P1/P3/P5/P7 with barrier — every gated load has >=4 phases of flight.
// Barriers only at gate phases (4 per iter); WAR: each stage targets a region
// whose last read is separated by >=1 barrier (wave skew <=1 phase is safe).
// 2D XCD mapping: each XCD owns an 8x8 square of 256-tiles (L2-resident).

#define STAGE(SB, BUFSEL, REGOFF, HALF, KT) do {                                   \
    const u16* _s0 = (SB) + (size_t)(HALF) * (128 * (size_t)KDIM) + (KT) * 64;     \
    u16* _d0 = lds + (BUFSEL) * 32768 + (REGOFF) + (HALF) * 8192 + wave * 1024;    \
    __builtin_amdgcn_global_load_lds(                                              \
        (const __attribute__((address_space(1))) void*)_s0,                        \
        (__attribute__((address_space(3))) void*)_d0, 16, 0, 0);                   \
    __builtin_amdgcn_global_load_lds(                                              \
        (const __attribute__((address_space(1))) void*)(_s0 + 8 * KDIM),           \
        (__attribute__((address_space(3))) void*)(_d0 + 512), 16, 0, 0);           \
  } while (0)

#define SBAR0 __builtin_amdgcn_sched_barrier(0)

#define GATE(N) do {                                                               \
    asm volatile("s_waitcnt vmcnt(" #N ")" ::: "memory");                          \
    SBAR0;                                                                         \
    __builtin_amdgcn_s_barrier();                                                  \
    SBAR0;                                                                         \
  } while (0)

// one phase: reads (A always, B if LOADB), stage-issue, 16 MFMA
#define COMPUTE(BUF, QM, KK, LOADB, STAGE_STMT) do {                               \
    bf16x8 af[4];                                                                  \
    {                                                                              \
      int _ab = (BUF) * 32768 + (QM) * 8192 + aRowBase;                            \
      if (KK) _ab ^= 32;                                                           \
      _Pragma("unroll")                                                            \
      for (int mf = 0; mf < 4; ++mf)                                               \
        af[mf] = *(const bf16x8*)(lds + (_ab + mf * 1024));                        \
      if (LOADB) {                                                                 \
        int _bb = (BUF) * 32768 + bRowBase;                                        \
        if (KK) _bb ^= 32;                                                         \
        _Pragma("unroll")                                                          \
        for (int nf = 0; nf < 4; ++nf)                                             \
          bfr[nf][KK] = *(const bf16x8*)(lds + (_bb + nf * 1024));                 \
      }                                                                            \
    }                                                                              \
    SBAR0;                                                                         \
    STAGE_STMT;                                                                    \
    SBAR0;                                                                         \
    __builtin_amdgcn_s_setprio(1);                                                 \
    _Pragma("unroll")                                                              \
    for (int mf = 0; mf < 4; ++mf)                                                 \
      _Pragma("unroll")                                                            \
      for (int nf = 0; nf < 4; ++nf)                                               \
        acc[QM][mf][nf] = __builtin_amdgcn_mfma_f32_16x16x32_bf16(                 \
            af[mf], bfr[nf][KK], acc[QM][mf][nf], 0, 0, 0);                        \
    __builtin_amdgcn_s_setprio(0);                                                 \
    SBAR0;                                                                         \
  } while (0)

__global__ __launch_bounds__(512, 2) void qlora_gemm_sp(const u16* __restrict__ A,
                                                        const u16* __restrict__ B,
                                                        float* __restrict__ C) {
  __shared__ __align__(16) u16 lds[65536];  // 128 KiB: buf{0,1} x (A 32KB + B 32KB)

  const int t = threadIdx.x;
  const int lane = t & 63;
  const int wave = t >> 6;          // 0..7
  const int wr = wave >> 2;         // 0..1  (M)
  const int wc = wave & 3;          // 0..3  (N)
  const int lrow = lane & 15;
  const int khalf = lane >> 4;      // 0..3
  const int g0 = (khalf ^ (lane & 7)) * 8; // swizzled granule (u16 units)

  // 2D XCD mapping: XCD = flat&7 owns an 8x8 square of 256-tiles (L2-resident)
  const int flat = blockIdx.x;
  const int xcd = flat & 7;
  const int idx = flat >> 3;                       // 0..63
  const int brow = ((xcd & 3) * 8 + (idx & 7)) * 256;
  const int bcol = ((xcd >> 2) * 8 + (idx >> 3)) * 256;

  // per-thread LDS read bases (u16 units), swizzle g0 folded in
  const int aRowBase = (wr * 64 + lrow) * 64 + g0;
  const int bRowBase = 16384 + (wc * 64 + lrow) * 64 + g0;

  // per-thread pre-swizzled global staging bases:
  // row = wave*16 + L*8 + (lane>>3), granule = (lane&7) ^ ((lane>>3)&7)
  const int srow = wave * 16 + (lane >> 3);
  const int sg = ((lane & 7) ^ ((lane >> 3) & 7)) * 8;
  const u16* aS = A + (size_t)(brow + srow) * KDIM + sg;
  const u16* bS = B + (size_t)(bcol + srow) * KDIM + sg;

  f32x4 acc[2][4][4] = {};
  bf16x8 bfr[4][2];

  // ---- prologue: buf0 <- tile0 (A0,B0,B1,A1), buf1 <- tile1 (A0,B0) ----
  STAGE(aS, 0, 0, 0, 0);
  STAGE(bS, 0, 16384, 0, 0);
  STAGE(bS, 0, 16384, 1, 0);
  STAGE(aS, 0, 0, 1, 0);
  STAGE(aS, 1, 0, 0, 1);
  STAGE(bS, 1, 16384, 0, 1);
  SBAR0;

#pragma unroll 1
  for (int it = 0; it < KDIM / 128; ++it) {
    const int o1 = 2 * it + 1;            // current odd tile (buf1)
    const int e2 = (2 * it + 2) & 63;     // next even tile (buf0)
    const int o3 = (2 * it + 3) & 63;     // next odd tile (buf1)

    GATE(6);                                             // A0,B0,B1(e) landed
    COMPUTE(0, 0, 0, 1, STAGE(bS, 1, 16384, 1, o1));     // P1 + B1(o)->buf1
    COMPUTE(0, 0, 1, 1, STAGE(aS, 1, 0, 1, o1));         // P2 + A1(o)->buf1
    GATE(8);                                             // A1(e) landed
    COMPUTE(0, 1, 0, 0, STAGE(aS, 0, 0, 0, e2));         // P3 + A0(e')->buf0
    COMPUTE(0, 1, 1, 0, STAGE(bS, 0, 16384, 0, e2));     // P4 + B0(e')->buf0
    GATE(6);                                             // A0,B0,B1(o) landed
    COMPUTE(1, 0, 0, 1, STAGE(bS, 0, 16384, 1, e2));     // P5 + B1(e')->buf0
    COMPUTE(1, 0, 1, 1, STAGE(aS, 0, 0, 1, e2));         // P6 + A1(e')->buf0
    GATE(8);                                             // A1(o) landed
    COMPUTE(1, 1, 0, 0, STAGE(aS, 1, 0, 0, o3));         // P7 + A0(o')->buf1
    COMPUTE(1, 1, 1, 0, STAGE(bS, 1, 16384, 0, o3));     // P8 + B0(o')->buf1
  }

  asm volatile("s_waitcnt vmcnt(0) lgkmcnt(0)" ::: "memory");

  // ---- epilogue: C/D layout col=lane&15, row=(lane>>4)*4+q ----
  float* Cb = C + (size_t)brow * NDIM + bcol;
  const int rb = wr * 64 + (lane >> 4) * 4;
  const int cb = wc * 64 + lrow;
#pragma unroll
  for (int qm = 0; qm < 2; ++qm)
#pragma unroll
    for (int mf = 0; mf < 4; ++mf)
#pragma unroll
      for (int nf = 0; nf < 4; ++nf) {
        const int r = qm * 128 + rb + mf * 16;
        const int c = cb + nf * 16;
        f32x4 v = acc[qm][mf][nf];
#pragma unroll
        for (int q = 0; q < 4; ++q)
          Cb[(size_t)(r + q) * NDIM + c] = v[q];
      }
}

// ---------------- fallback: fp32 tiled GEMM with on-the-fly dequant (no ws) ----------------
__global__ void qlora_fallback(const float* __restrict__ X, const int* __restrict__ qw,
                               const void* __restrict__ sc, const void* __restrict__ zr,
                               const float* __restrict__ lA, const float* __restrict__ lB,
                               float* __restrict__ C) {
  __shared__ float Xs[32][65];
  __shared__ float Ws[32][65];
  const int t = threadIdx.x;
  const bool f32 = sz_is_f32(sc);
  const int brow = blockIdx.x * 64, bcol = blockIdx.y * 64;
  const int tr = t >> 4, tc = t & 15;
  float acc[4][4] = {};
  for (int k0 = 0; k0 < KDIM; k0 += 32) {
    __syncthreads();
    {
      int row = t >> 2;
      int kk0 = (t & 3) * 8;
      const float* src = X + (size_t)(brow + row) * KDIM + k0 + kk0;
#pragma unroll
      for (int u = 0; u < 8; ++u) Xs[kk0 + u][row] = src[u];
    }
    {
      int o = t >> 2;
      int kk0 = (t & 3) * 8;
      int oo = bcol + o;
      float s = load_sz(sc, oo, f32), z = load_sz(zr, oo, f32);
      const int* qrow = qw + (size_t)oo * (KDIM / 2) + (k0 + kk0) / 2;
#pragma unroll
      for (int u = 0; u < 4; ++u) {
        int q = qrow[u];
        int kk = kk0 + u * 2;
        float l0 = 0.f, l1 = 0.f;
#pragma unroll
        for (int r = 0; r < 16; ++r) {
          float br = lB[oo * 16 + r] * 2.0f;
          l0 += br * lA[(size_t)r * KDIM + k0 + kk];
          l1 += br * lA[(size_t)r * KDIM + k0 + kk + 1];
        }
        Ws[kk][o] = (float)((q >> 4) & 15) * s + z + l0;
        Ws[kk + 1][o] = (float)(q & 15) * s + z + l1;
      }
    }
    __syncthreads();
#pragma unroll
    for (int k = 0; k < 32; ++k) {
      float xv[4], wv[4];
#pragma unroll
      for (int i = 0; i < 4; ++i) xv[i] = Xs[k][tr * 4 + i];
#pragma unroll
      for (int j = 0; j < 4; ++j) wv[j] = Ws[k][tc * 4 + j];
#pragma unroll
      for (int i = 0; i < 4; ++i)
#pragma unroll
        for (int j = 0; j < 4; ++j) acc[i][j] += xv[i] * wv[j];
    }
  }
#pragma unroll
  for (int i = 0; i < 4; ++i)
#pragma unroll
    for (int j = 0; j < 4; ++j)
      C[(size_t)(brow + tr * 4 + i) * NDIM + bcol + tc * 4 + j] = acc[i][j];
}

extern "C" void kernel_launch(void* const* d_in, const int* in_sizes, int n_in,
                              void* d_out, int out_size, void* d_ws, size_t ws_size,
                              hipStream_t stream) {
  const float* x = (const float*)d_in[0];
  const int* qw = (const int*)d_in[1];
  const void* sc = d_in[2];
  const void* zr = d_in[3];
  const float* lA = (const float*)d_in[4];
  const float* lB = (const float*)d_in[5];
  float* out = (float*)d_out;

  const size_t xb_bytes = (size_t)MDIM * KDIM * 2;
  const size_t weff_bytes = (size_t)NDIM * KDIM * 2;
  if (ws_size >= xb_bytes + weff_bytes) {
    u16* xb = (u16*)d_ws;
    u16* weff = xb + (size_t)MDIM * KDIM;
    qlora_prep<<<CONVB + WEFFB, 256, 0, stream>>>((const float4*)x, (ushort4*)xb,
                                                  qw, sc, zr, lA, lB, (ushort2*)weff);
    dim3 grid((MDIM / 256) * (NDIM / 256));  // 512 blocks
    qlora_gemm_sp<<<grid, 512, 0, stream>>>(xb, weff, out);
  } else {
    dim3 grid(MDIM / 64, NDIM / 64);
    qlora_fallback<<<grid, 256, 0, stream>>>(x, qw, sc, zr, lA, lB, out);
  }
}

// Round 12
// 279.450 us; speedup vs baseline: 1.1656x; 1.0320x over previous
//
#include <hip/hip_runtime.h>
#include <hip/hip_fp16.h>

#define MDIM 8192   // B*S = 4*2048
#define NDIM 4096   // OUT
#define KDIM 4096   // IN

typedef unsigned short u16;
typedef __bf16 bf16x8 __attribute__((ext_vector_type(8)));
typedef float f32x4 __attribute__((ext_vector_type(4)));
typedef float fv4 __attribute__((ext_vector_type(4)));   // native vec for nontemporal builtins

static __device__ __forceinline__ u16 f2bf(float f) {
  union { float f; unsigned u; } v; v.f = f;
  unsigned r = v.u + 0x7fffu + ((v.u >> 16) & 1u);  // round-to-nearest-even
  return (u16)(r >> 16);
}

// scales/zeros may arrive as fp16 (reference dtype) or promoted to fp32.
static __device__ __forceinline__ bool sz_is_f32(const void* sc) {
  unsigned w0 = ((const unsigned*)sc)[0];
  return ((w0 >> 16) & 0x7fffu) >= 0x3000u;
}
static __device__ __forceinline__ float load_sz(const void* p, int i, bool f32) {
  return f32 ? ((const float*)p)[i] : __half2float(((const __half*)p)[i]);
}

// ---------------- kernel 1: fused {x fp32->bf16 conv} + {dequant+LoRA W_eff} ----------------
// conv: blocks [0, CONVB) — nontemporal x loads (read-once data).
// weff: blocks [CONVB, CONVB+WEFFB): 1024 blocks of 32 O x 512 I; lA slice
// (32KB) + lB tile + scales/zeros in LDS; 32-iteration o-loop (2x parallelism
// vs round 10's 64) to hide the dependent qw loads.
#define CONVB 2048
#define WEFFB 1024
__global__ void qlora_prep(const float* __restrict__ x, ushort4* __restrict__ xb,
                           const int* __restrict__ qw, const void* __restrict__ sc,
                           const void* __restrict__ zr, const float* __restrict__ lA,
                           const float* __restrict__ lB, ushort2* __restrict__ weff) {
  if (blockIdx.x < CONVB) {
    unsigned base = blockIdx.x * 256u + threadIdx.x;
#pragma unroll
    for (int s = 0; s < 16; ++s) {
      unsigned i = base + (unsigned)s * (CONVB * 256u);
      fv4 a = __builtin_nontemporal_load((const fv4*)x + i);
      ushort4 o;
      o.x = f2bf(a.x); o.y = f2bf(a.y); o.z = f2bf(a.z); o.w = f2bf(a.w);
      xb[i] = o;
    }
  } else {
    __shared__ __align__(16) float lA_s[16][512];
    __shared__ float lB_s[32][16];
    __shared__ float s_s[32], z_s[32];
    const int bid = blockIdx.x - CONVB;        // 0..1023
    const int t = threadIdx.x;
    const int o0 = (bid & 127) * 32;           // O-tile (32 rows)
    const int it0 = (bid >> 7) * 512;          // I-tile (512 cols)
    const bool f32 = sz_is_f32(sc);
    // stage lA[16][it0:it0+512] (2048 float4, 8 per thread)
#pragma unroll
    for (int s = 0; s < 8; ++s) {
      int idx = s * 256 + t;
      int r = idx >> 7, c4 = idx & 127;
      *(float4*)&lA_s[r][c4 * 4] = *(const float4*)(lA + (size_t)r * KDIM + it0 + c4 * 4);
    }
    // stage lB[o0:o0+32][16] * SCALING (512 floats, 2 per thread)
#pragma unroll
    for (int s = 0; s < 2; ++s) {
      int idx = s * 256 + t;
      int o = idx >> 4, r = idx & 15;
      lB_s[o][r] = lB[(o0 + o) * 16 + r] * 2.0f;   // SCALING = 32/16
    }
    if (t < 32) {
      s_s[t] = load_sz(sc, o0 + t, f32);
      z_s[t] = load_sz(zr, o0 + t, f32);
    }
    __syncthreads();
    // hoist this thread's lA column pair (fixed across o)
    float2 a2[16];
#pragma unroll
    for (int r = 0; r < 16; ++r) a2[r] = *(const float2*)&lA_s[r][2 * t];
    const size_t i2 = (size_t)(it0 / 2 + t);
    const int* qcol = qw + i2;
    ushort2* wcol = weff + i2;
#pragma unroll 4
    for (int o = 0; o < 32; ++o) {
      const int oo = o0 + o;
      int q = qcol[(size_t)oo * (KDIM / 2)];
      float acc0 = 0.f, acc1 = 0.f;
#pragma unroll
      for (int r = 0; r < 16; ++r) {
        float br = lB_s[o][r];
        acc0 += br * a2[r].x;
        acc1 += br * a2[r].y;
      }
      const float s = s_s[o], z = z_s[o];
      float w0 = (float)((q >> 4) & 15) * s + z + acc0;   // high nibble -> even col
      float w1 = (float)(q & 15) * s + z + acc1;          // low nibble -> odd col
      ushort2 pk; pk.x = f2bf(w0); pk.y = f2bf(w1);
      wcol[(size_t)oo * (KDIM / 2)] = pk;
    }
  }
}

// ---------------- kernel 2: 256x256 staggered 8-phase bf16 MFMA GEMM ----------------
// (round-10 winner, unchanged except nontemporal C stores)
// 8 phases / 2 K-tiles: one half-tile stage per phase in fixed order
// [B1(o),A1(o),A0(e'),B0(e'),B1(e'),A1(e'),A0(o'),B0(o')]; gates vmcnt(6/8/6/8)
// at P1/P3/P5/P7 — every gated load has >=4 phases (~1200+ cyc) of flight.
// 2D XCD mapping: each XCD owns an 8x8 square of 256-tiles (L2-resident).

#define STAGE(SB, BUFSEL, REGOFF, HALF, KT) do {                                   \
    const u16* _s0 = (SB) + (size_t)(HALF) * (128 * (size_t)KDIM) + (KT) * 64;     \
    u16* _d0 = lds + (BUFSEL) * 32768 + (REGOFF) + (HALF) * 8192 + wave * 1024;    \
    __builtin_amdgcn_global_load_lds(                                              \
        (const __attribute__((address_space(1))) void*)_s0,                        \
        (__attribute__((address_space(3))) void*)_d0, 16, 0, 0);                   \
    __builtin_amdgcn_global_load_lds(                                              \
        (const __attribute__((address_space(1))) void*)(_s0 + 8 * KDIM),           \
        (__attribute__((address_space(3))) void*)(_d0 + 512), 16, 0, 0);           \
  } while (0)

#define SBAR0 __builtin_amdgcn_sched_barrier(0)

#define GATE(N) do {                                                               \
    asm volatile("s_waitcnt vmcnt(" #N ")" ::: "memory");                          \
    SBAR0;                                                                         \
    __builtin_amdgcn_s_barrier();                                                  \
    SBAR0;                                                                         \
  } while (0)

// one phase: reads (A always, B if LOADB), stage-issue, 16 MFMA
#define COMPUTE(BUF, QM, KK, LOADB, STAGE_STMT) do {                               \
    bf16x8 af[4];                                                                  \
    {                                                                              \
      int _ab = (BUF) * 32768 + (QM) * 8192 + aRowBase;                            \
      if (KK) _ab ^= 32;                                                           \
      _Pragma("unroll")                                                            \
      for (int mf = 0; mf < 4; ++mf)                                               \
        af[mf] = *(const bf16x8*)(lds + (_ab + mf * 1024));                        \
      if (LOADB) {                                                                 \
        int _bb = (BUF) * 32768 + bRowBase;                                        \
        if (KK) _bb ^= 32;                                                         \
        _Pragma("unroll")                                                          \
        for (int nf = 0; nf < 4; ++nf)                                             \
          bfr[nf][KK] = *(const bf16x8*)(lds + (_bb + nf * 1024));                 \
      }                                                                            \
    }                                                                              \
    SBAR0;                                                                         \
    STAGE_STMT;                                                                    \
    SBAR0;                                                                         \
    __builtin_amdgcn_s_setprio(1);                                                 \
    _Pragma("unroll")                                                              \
    for (int mf = 0; mf < 4; ++mf)                                                 \
      _Pragma("unroll")                                                            \
      for (int nf = 0; nf < 4; ++nf)                                               \
        acc[QM][mf][nf] = __builtin_amdgcn_mfma_f32_16x16x32_bf16(                 \
            af[mf], bfr[nf][KK], acc[QM][mf][nf], 0, 0, 0);                        \
    __builtin_amdgcn_s_setprio(0);                                                 \
    SBAR0;                                                                         \
  } while (0)

__global__ __launch_bounds__(512, 2) void qlora_gemm_sp(const u16* __restrict__ A,
                                                        const u16* __restrict__ B,
                                                        float* __restrict__ C) {
  __shared__ __align__(16) u16 lds[65536];  // 128 KiB: buf{0,1} x (A 32KB + B 32KB)

  const int t = threadIdx.x;
  const int lane = t & 63;
  const int wave = t >> 6;          // 0..7
  const int wr = wave >> 2;         // 0..1  (M)
  const int wc = wave & 3;          // 0..3  (N)
  const int lrow = lane & 15;
  const int khalf = lane >> 4;      // 0..3
  const int g0 = (khalf ^ (lane & 7)) * 8; // swizzled granule (u16 units)

  // 2D XCD mapping: XCD = flat&7 owns an 8x8 square of 256-tiles (L2-resident)
  const int flat = blockIdx.x;
  const int xcd = flat & 7;
  const int idx = flat >> 3;                       // 0..63
  const int brow = ((xcd & 3) * 8 + (idx & 7)) * 256;
  const int bcol = ((xcd >> 2) * 8 + (idx >> 3)) * 256;

  // per-thread LDS read bases (u16 units), swizzle g0 folded in
  const int aRowBase = (wr * 64 + lrow) * 64 + g0;
  const int bRowBase = 16384 + (wc * 64 + lrow) * 64 + g0;

  // per-thread pre-swizzled global staging bases:
  // row = wave*16 + L*8 + (lane>>3), granule = (lane&7) ^ ((lane>>3)&7)
  const int srow = wave * 16 + (lane >> 3);
  const int sg = ((lane & 7) ^ ((lane >> 3) & 7)) * 8;
  const u16* aS = A + (size_t)(brow + srow) * KDIM + sg;
  const u16* bS = B + (size_t)(bcol + srow) * KDIM + sg;

  f32x4 acc[2][4][4] = {};
  bf16x8 bfr[4][2];

  // ---- prologue: buf0 <- tile0 (A0,B0,B1,A1), buf1 <- tile1 (A0,B0) ----
  STAGE(aS, 0, 0, 0, 0);
  STAGE(bS, 0, 16384, 0, 0);
  STAGE(bS, 0, 16384, 1, 0);
  STAGE(aS, 0, 0, 1, 0);
  STAGE(aS, 1, 0, 0, 1);
  STAGE(bS, 1, 16384, 0, 1);
  SBAR0;

#pragma unroll 1
  for (int it = 0; it < KDIM / 128; ++it) {
    const int o1 = 2 * it + 1;            // current odd tile (buf1)
    const int e2 = (2 * it + 2) & 63;     // next even tile (buf0)
    const int o3 = (2 * it + 3) & 63;     // next odd tile (buf1)

    GATE(6);                                             // A0,B0,B1(e) landed
    COMPUTE(0, 0, 0, 1, STAGE(bS, 1, 16384, 1, o1));     // P1 + B1(o)->buf1
    COMPUTE(0, 0, 1, 1, STAGE(aS, 1, 0, 1, o1));         // P2 + A1(o)->buf1
    GATE(8);                                             // A1(e) landed
    COMPUTE(0, 1, 0, 0, STAGE(aS, 0, 0, 0, e2));         // P3 + A0(e')->buf0
    COMPUTE(0, 1, 1, 0, STAGE(bS, 0, 16384, 0, e2));     // P4 + B0(e')->buf0
    GATE(6);                                             // A0,B0,B1(o) landed
    COMPUTE(1, 0, 0, 1, STAGE(bS, 0, 16384, 1, e2));     // P5 + B1(e')->buf0
    COMPUTE(1, 0, 1, 1, STAGE(aS, 0, 0, 1, e2));         // P6 + A1(e')->buf0
    GATE(8);                                             // A1(o) landed
    COMPUTE(1, 1, 0, 0, STAGE(aS, 1, 0, 0, o3));         // P7 + A0(o')->buf1
    COMPUTE(1, 1, 1, 0, STAGE(bS, 1, 16384, 0, o3));     // P8 + B0(o')->buf1
  }

  asm volatile("s_waitcnt vmcnt(0) lgkmcnt(0)" ::: "memory");

  // ---- epilogue: C/D layout col=lane&15, row=(lane>>4)*4+q; nontemporal C ----
  float* Cb = C + (size_t)brow * NDIM + bcol;
  const int rb = wr * 64 + (lane >> 4) * 4;
  const int cb = wc * 64 + lrow;
#pragma unroll
  for (int qm = 0; qm < 2; ++qm)
#pragma unroll
    for (int mf = 0; mf < 4; ++mf)
#pragma unroll
      for (int nf = 0; nf < 4; ++nf) {
        const int r = qm * 128 + rb + mf * 16;
        const int c = cb + nf * 16;
        f32x4 v = acc[qm][mf][nf];
#pragma unroll
        for (int q = 0; q < 4; ++q)
          __builtin_nontemporal_store(v[q], &Cb[(size_t)(r + q) * NDIM + c]);
      }
}

// ---------------- fallback: fp32 tiled GEMM with on-the-fly dequant (no ws) ----------------
__global__ void qlora_fallback(const float* __restrict__ X, const int* __restrict__ qw,
                               const void* __restrict__ sc, const void* __restrict__ zr,
                               const float* __restrict__ lA, const float* __restrict__ lB,
                               float* __restrict__ C) {
  __shared__ float Xs[32][65];
  __shared__ float Ws[32][65];
  const int t = threadIdx.x;
  const bool f32 = sz_is_f32(sc);
  const int brow = blockIdx.x * 64, bcol = blockIdx.y * 64;
  const int tr = t >> 4, tc = t & 15;
  float acc[4][4] = {};
  for (int k0 = 0; k0 < KDIM; k0 += 32) {
    __syncthreads();
    {
      int row = t >> 2;
      int kk0 = (t & 3) * 8;
      const float* src = X + (size_t)(brow + row) * KDIM + k0 + kk0;
#pragma unroll
      for (int u = 0; u < 8; ++u) Xs[kk0 + u][row] = src[u];
    }
    {
      int o = t >> 2;
      int kk0 = (t & 3) * 8;
      int oo = bcol + o;
      float s = load_sz(sc, oo, f32), z = load_sz(zr, oo, f32);
      const int* qrow = qw + (size_t)oo * (KDIM / 2) + (k0 + kk0) / 2;
#pragma unroll
      for (int u = 0; u < 4; ++u) {
        int q = qrow[u];
        int kk = kk0 + u * 2;
        float l0 = 0.f, l1 = 0.f;
#pragma unroll
        for (int r = 0; r < 16; ++r) {
          float br = lB[oo * 16 + r] * 2.0f;
          l0 += br * lA[(size_t)r * KDIM + k0 + kk];
          l1 += br * lA[(size_t)r * KDIM + k0 + kk + 1];
        }
        Ws[kk][o] = (float)((q >> 4) & 15) * s + z + l0;
        Ws[kk + 1][o] = (float)(q & 15) * s + z + l1;
      }
    }
    __syncthreads();
#pragma unroll
    for (int k = 0; k < 32; ++k) {
      float xv[4], wv[4];
#pragma unroll
      for (int i = 0; i < 4; ++i) xv[i] = Xs[k][tr * 4 + i];
#pragma unroll
      for (int j = 0; j < 4; ++j) wv[j] = Ws[k][tc * 4 + j];
#pragma unroll
      for (int i = 0; i < 4; ++i)
#pragma unroll
        for (int j = 0; j < 4; ++j) acc[i][j] += xv[i] * wv[j];
    }
  }
#pragma unroll
  for (int i = 0; i < 4; ++i)
#pragma unroll
    for (int j = 0; j < 4; ++j)
      C[(size_t)(brow + tr * 4 + i) * NDIM + bcol + tc * 4 + j] = acc[i][j];
}

extern "C" void kernel_launch(void* const* d_in, const int* in_sizes, int n_in,
                              void* d_out, int out_size, void* d_ws, size_t ws_size,
                              hipStream_t stream) {
  const float* x = (const float*)d_in[0];
  const int* qw = (const int*)d_in[1];
  const void* sc = d_in[2];
  const void* zr = d_in[3];
  const float* lA = (const float*)d_in[4];
  const float* lB = (const float*)d_in[5];
  float* out = (float*)d_out;

  const size_t xb_bytes = (size_t)MDIM * KDIM * 2;
  const size_t weff_bytes = (size_t)NDIM * KDIM * 2;
  if (ws_size >= xb_bytes + weff_bytes) {
    u16* xb = (u16*)d_ws;
    u16* weff = xb + (size_t)MDIM * KDIM;
    qlora_prep<<<CONVB + WEFFB, 256, 0, stream>>>(x, (ushort4*)xb,
                                                  qw, sc, zr, lA, lB, (ushort2*)weff);
    dim3 grid((MDIM / 256) * (NDIM / 256));  // 512 blocks
    qlora_gemm_sp<<<grid, 512, 0, stream>>>(xb, weff, out);
  } else {
    dim3 grid(MDIM / 64, NDIM / 64);
    qlora_fallback<<<grid, 256, 0, stream>>>(x, qw, sc, zr, lA, lB, out);
  }
}

// Round 13
// 265.659 us; speedup vs baseline: 1.2261x; 1.0519x over previous
//
#include <hip/hip_runtime.h>
#include <hip/hip_fp16.h>

#define MDIM 8192   // B*S = 4*2048
#define NDIM 4096   // OUT
#define KDIM 4096   // IN

typedef unsigned short u16;
typedef __bf16 bf16x8 __attribute__((ext_vector_type(8)));
typedef float f32x4 __attribute__((ext_vector_type(4)));
typedef float fv4 __attribute__((ext_vector_type(4)));   // native vec for nontemporal builtins

static __device__ __forceinline__ u16 f2bf(float f) {
  union { float f; unsigned u; } v; v.f = f;
  unsigned r = v.u + 0x7fffu + ((v.u >> 16) & 1u);  // round-to-nearest-even
  return (u16)(r >> 16);
}

// scales/zeros may arrive as fp16 (reference dtype) or promoted to fp32.
static __device__ __forceinline__ bool sz_is_f32(const void* sc) {
  unsigned w0 = ((const unsigned*)sc)[0];
  return ((w0 >> 16) & 0x7fffu) >= 0x3000u;
}
static __device__ __forceinline__ float load_sz(const void* p, int i, bool f32) {
  return f32 ? ((const float*)p)[i] : __half2float(((const __half*)p)[i]);
}

// ---------------- kernel 1: fused {x fp32->bf16 conv} + {dequant+LoRA W_eff} ----------------
// conv: blocks [0, CONVB) — nontemporal x loads (read-once data).
// weff: blocks [CONVB, CONVB+WEFFB): 1024 blocks of 32 O x 512 I; lA slice
// (32KB) + lB tile + scales/zeros in LDS; 32-iteration o-loop to hide the
// dependent qw loads.
#define CONVB 2048
#define WEFFB 1024
__global__ void qlora_prep(const float* __restrict__ x, ushort4* __restrict__ xb,
                           const int* __restrict__ qw, const void* __restrict__ sc,
                           const void* __restrict__ zr, const float* __restrict__ lA,
                           const float* __restrict__ lB, ushort2* __restrict__ weff) {
  if (blockIdx.x < CONVB) {
    unsigned base = blockIdx.x * 256u + threadIdx.x;
#pragma unroll
    for (int s = 0; s < 16; ++s) {
      unsigned i = base + (unsigned)s * (CONVB * 256u);
      fv4 a = __builtin_nontemporal_load((const fv4*)x + i);
      ushort4 o;
      o.x = f2bf(a.x); o.y = f2bf(a.y); o.z = f2bf(a.z); o.w = f2bf(a.w);
      xb[i] = o;
    }
  } else {
    __shared__ __align__(16) float lA_s[16][512];
    __shared__ float lB_s[32][16];
    __shared__ float s_s[32], z_s[32];
    const int bid = blockIdx.x - CONVB;        // 0..1023
    const int t = threadIdx.x;
    const int o0 = (bid & 127) * 32;           // O-tile (32 rows)
    const int it0 = (bid >> 7) * 512;          // I-tile (512 cols)
    const bool f32 = sz_is_f32(sc);
    // stage lA[16][it0:it0+512] (2048 float4, 8 per thread)
#pragma unroll
    for (int s = 0; s < 8; ++s) {
      int idx = s * 256 + t;
      int r = idx >> 7, c4 = idx & 127;
      *(float4*)&lA_s[r][c4 * 4] = *(const float4*)(lA + (size_t)r * KDIM + it0 + c4 * 4);
    }
    // stage lB[o0:o0+32][16] * SCALING (512 floats, 2 per thread)
#pragma unroll
    for (int s = 0; s < 2; ++s) {
      int idx = s * 256 + t;
      int o = idx >> 4, r = idx & 15;
      lB_s[o][r] = lB[(o0 + o) * 16 + r] * 2.0f;   // SCALING = 32/16
    }
    if (t < 32) {
      s_s[t] = load_sz(sc, o0 + t, f32);
      z_s[t] = load_sz(zr, o0 + t, f32);
    }
    __syncthreads();
    // hoist this thread's lA column pair (fixed across o)
    float2 a2[16];
#pragma unroll
    for (int r = 0; r < 16; ++r) a2[r] = *(const float2*)&lA_s[r][2 * t];
    const size_t i2 = (size_t)(it0 / 2 + t);
    const int* qcol = qw + i2;
    ushort2* wcol = weff + i2;
#pragma unroll 4
    for (int o = 0; o < 32; ++o) {
      const int oo = o0 + o;
      int q = qcol[(size_t)oo * (KDIM / 2)];
      float acc0 = 0.f, acc1 = 0.f;
#pragma unroll
      for (int r = 0; r < 16; ++r) {
        float br = lB_s[o][r];
        acc0 += br * a2[r].x;
        acc1 += br * a2[r].y;
      }
      const float s = s_s[o], z = z_s[o];
      float w0 = (float)((q >> 4) & 15) * s + z + acc0;   // high nibble -> even col
      float w1 = (float)(q & 15) * s + z + acc1;          // low nibble -> odd col
      ushort2 pk; pk.x = f2bf(w0); pk.y = f2bf(w1);
      wcol[(size_t)oo * (KDIM / 2)] = pk;
    }
  }
}

// ---------------- kernel 2: 256x256 staggered 8-phase bf16 MFMA GEMM ----------------
// (round-10 winner; plain C stores — nontemporal stores measured +20% WRITE_SIZE)
// 8 phases / 2 K-tiles: one half-tile stage per phase in fixed order
// [B1(o),A1(o),A0(e'),B0(e'),B1(e'),A1(e'),A0(o'),B0(o')]; gates vmcnt(6/8/6/8)
// at P1/P3/P5/P7 — every gated load has >=4 phases (~1200+ cyc) of flight.
// 2D XCD mapping: each XCD owns an 8x8 square of 256-tiles (L2-resident).

#define STAGE(SB, BUFSEL, REGOFF, HALF, KT) do {                                   \
    const u16* _s0 = (SB) + (size_t)(HALF) * (128 * (size_t)KDIM) + (KT) * 64;     \
    u16* _d0 = lds + (BUFSEL) * 32768 + (REGOFF) + (HALF) * 8192 + wave * 1024;    \
    __builtin_amdgcn_global_load_lds(                                              \
        (const __attribute__((address_space(1))) void*)_s0,                        \
        (__attribute__((address_space(3))) void*)_d0, 16, 0, 0);                   \
    __builtin_amdgcn_global_load_lds(                                              \
        (const __attribute__((address_space(1))) void*)(_s0 + 8 * KDIM),           \
        (__attribute__((address_space(3))) void*)(_d0 + 512), 16, 0, 0);           \
  } while (0)

#define SBAR0 __builtin_amdgcn_sched_barrier(0)

#define GATE(N) do {                                                               \
    asm volatile("s_waitcnt vmcnt(" #N ")" ::: "memory");                          \
    SBAR0;                                                                         \
    __builtin_amdgcn_s_barrier();                                                  \
    SBAR0;                                                                         \
  } while (0)

// one phase: reads (A always, B if LOADB), stage-issue, 16 MFMA
#define COMPUTE(BUF, QM, KK, LOADB, STAGE_STMT) do {                               \
    bf16x8 af[4];                                                                  \
    {                                                                              \
      int _ab = (BUF) * 32768 + (QM) * 8192 + aRowBase;                            \
      if (KK) _ab ^= 32;                                                           \
      _Pragma("unroll")                                                            \
      for (int mf = 0; mf < 4; ++mf)                                               \
        af[mf] = *(const bf16x8*)(lds + (_ab + mf * 1024));                        \
      if (LOADB) {                                                                 \
        int _bb = (BUF) * 32768 + bRowBase;                                        \
        if (KK) _bb ^= 32;                                                         \
        _Pragma("unroll")                                                          \
        for (int nf = 0; nf < 4; ++nf)                                             \
          bfr[nf][KK] = *(const bf16x8*)(lds + (_bb + nf * 1024));                 \
      }                                                                            \
    }                                                                              \
    SBAR0;                                                                         \
    STAGE_STMT;                                                                    \
    SBAR0;                                                                         \
    __builtin_amdgcn_s_setprio(1);                                                 \
    _Pragma("unroll")                                                              \
    for (int mf = 0; mf < 4; ++mf)                                                 \
      _Pragma("unroll")                                                            \
      for (int nf = 0; nf < 4; ++nf)                                               \
        acc[QM][mf][nf] = __builtin_amdgcn_mfma_f32_16x16x32_bf16(                 \
            af[mf], bfr[nf][KK], acc[QM][mf][nf], 0, 0, 0);                        \
    __builtin_amdgcn_s_setprio(0);                                                 \
    SBAR0;                                                                         \
  } while (0)

__global__ __launch_bounds__(512, 2) void qlora_gemm_sp(const u16* __restrict__ A,
                                                        const u16* __restrict__ B,
                                                        float* __restrict__ C) {
  __shared__ __align__(16) u16 lds[65536];  // 128 KiB: buf{0,1} x (A 32KB + B 32KB)

  const int t = threadIdx.x;
  const int lane = t & 63;
  const int wave = t >> 6;          // 0..7
  const int wr = wave >> 2;         // 0..1  (M)
  const int wc = wave & 3;          // 0..3  (N)
  const int lrow = lane & 15;
  const int khalf = lane >> 4;      // 0..3
  const int g0 = (khalf ^ (lane & 7)) * 8; // swizzled granule (u16 units)

  // 2D XCD mapping: XCD = flat&7 owns an 8x8 square of 256-tiles (L2-resident)
  const int flat = blockIdx.x;
  const int xcd = flat & 7;
  const int idx = flat >> 3;                       // 0..63
  const int brow = ((xcd & 3) * 8 + (idx & 7)) * 256;
  const int bcol = ((xcd >> 2) * 8 + (idx >> 3)) * 256;

  // per-thread LDS read bases (u16 units), swizzle g0 folded in
  const int aRowBase = (wr * 64 + lrow) * 64 + g0;
  const int bRowBase = 16384 + (wc * 64 + lrow) * 64 + g0;

  // per-thread pre-swizzled global staging bases:
  // row = wave*16 + L*8 + (lane>>3), granule = (lane&7) ^ ((lane>>3)&7)
  const int srow = wave * 16 + (lane >> 3);
  const int sg = ((lane & 7) ^ ((lane >> 3) & 7)) * 8;
  const u16* aS = A + (size_t)(brow + srow) * KDIM + sg;
  const u16* bS = B + (size_t)(bcol + srow) * KDIM + sg;

  f32x4 acc[2][4][4] = {};
  bf16x8 bfr[4][2];

  // ---- prologue: buf0 <- tile0 (A0,B0,B1,A1), buf1 <- tile1 (A0,B0) ----
  STAGE(aS, 0, 0, 0, 0);
  STAGE(bS, 0, 16384, 0, 0);
  STAGE(bS, 0, 16384, 1, 0);
  STAGE(aS, 0, 0, 1, 0);
  STAGE(aS, 1, 0, 0, 1);
  STAGE(bS, 1, 16384, 0, 1);
  SBAR0;

#pragma unroll 1
  for (int it = 0; it < KDIM / 128; ++it) {
    const int o1 = 2 * it + 1;            // current odd tile (buf1)
    const int e2 = (2 * it + 2) & 63;     // next even tile (buf0)
    const int o3 = (2 * it + 3) & 63;     // next odd tile (buf1)

    GATE(6);                                             // A0,B0,B1(e) landed
    COMPUTE(0, 0, 0, 1, STAGE(bS, 1, 16384, 1, o1));     // P1 + B1(o)->buf1
    COMPUTE(0, 0, 1, 1, STAGE(aS, 1, 0, 1, o1));         // P2 + A1(o)->buf1
    GATE(8);                                             // A1(e) landed
    COMPUTE(0, 1, 0, 0, STAGE(aS, 0, 0, 0, e2));         // P3 + A0(e')->buf0
    COMPUTE(0, 1, 1, 0, STAGE(bS, 0, 16384, 0, e2));     // P4 + B0(e')->buf0
    GATE(6);                                             // A0,B0,B1(o) landed
    COMPUTE(1, 0, 0, 1, STAGE(bS, 0, 16384, 1, e2));     // P5 + B1(e')->buf0
    COMPUTE(1, 0, 1, 1, STAGE(aS, 0, 0, 1, e2));         // P6 + A1(e')->buf0
    GATE(8);                                             // A1(o) landed
    COMPUTE(1, 1, 0, 0, STAGE(aS, 1, 0, 0, o3));         // P7 + A0(o')->buf1
    COMPUTE(1, 1, 1, 0, STAGE(bS, 1, 16384, 0, o3));     // P8 + B0(o')->buf1
  }

  asm volatile("s_waitcnt vmcnt(0) lgkmcnt(0)" ::: "memory");

  // ---- epilogue: C/D layout col=lane&15, row=(lane>>4)*4+q ----
  float* Cb = C + (size_t)brow * NDIM + bcol;
  const int rb = wr * 64 + (lane >> 4) * 4;
  const int cb = wc * 64 + lrow;
#pragma unroll
  for (int qm = 0; qm < 2; ++qm)
#pragma unroll
    for (int mf = 0; mf < 4; ++mf)
#pragma unroll
      for (int nf = 0; nf < 4; ++nf) {
        const int r = qm * 128 + rb + mf * 16;
        const int c = cb + nf * 16;
        f32x4 v = acc[qm][mf][nf];
#pragma unroll
        for (int q = 0; q < 4; ++q)
          Cb[(size_t)(r + q) * NDIM + c] = v[q];
      }
}

// ---------------- fallback: fp32 tiled GEMM with on-the-fly dequant (no ws) ----------------
__global__ void qlora_fallback(const float* __restrict__ X, const int* __restrict__ qw,
                               const void* __restrict__ sc, const void* __restrict__ zr,
                               const float* __restrict__ lA, const float* __restrict__ lB,
                               float* __restrict__ C) {
  __shared__ float Xs[32][65];
  __shared__ float Ws[32][65];
  const int t = threadIdx.x;
  const bool f32 = sz_is_f32(sc);
  const int brow = blockIdx.x * 64, bcol = blockIdx.y * 64;
  const int tr = t >> 4, tc = t & 15;
  float acc[4][4] = {};
  for (int k0 = 0; k0 < KDIM; k0 += 32) {
    __syncthreads();
    {
      int row = t >> 2;
      int kk0 = (t & 3) * 8;
      const float* src = X + (size_t)(brow + row) * KDIM + k0 + kk0;
#pragma unroll
      for (int u = 0; u < 8; ++u) Xs[kk0 + u][row] = src[u];
    }
    {
      int o = t >> 2;
      int kk0 = (t & 3) * 8;
      int oo = bcol + o;
      float s = load_sz(sc, oo, f32), z = load_sz(zr, oo, f32);
      const int* qrow = qw + (size_t)oo * (KDIM / 2) + (k0 + kk0) / 2;
#pragma unroll
      for (int u = 0; u < 4; ++u) {
        int q = qrow[u];
        int kk = kk0 + u * 2;
        float l0 = 0.f, l1 = 0.f;
#pragma unroll
        for (int r = 0; r < 16; ++r) {
          float br = lB[oo * 16 + r] * 2.0f;
          l0 += br * lA[(size_t)r * KDIM + k0 + kk];
          l1 += br * lA[(size_t)r * KDIM + k0 + kk + 1];
        }
        Ws[kk][o] = (float)((q >> 4) & 15) * s + z + l0;
        Ws[kk + 1][o] = (float)(q & 15) * s + z + l1;
      }
    }
    __syncthreads();
#pragma unroll
    for (int k = 0; k < 32; ++k) {
      float xv[4], wv[4];
#pragma unroll
      for (int i = 0; i < 4; ++i) xv[i] = Xs[k][tr * 4 + i];
#pragma unroll
      for (int j = 0; j < 4; ++j) wv[j] = Ws[k][tc * 4 + j];
#pragma unroll
      for (int i = 0; i < 4; ++i)
#pragma unroll
        for (int j = 0; j < 4; ++j) acc[i][j] += xv[i] * wv[j];
    }
  }
#pragma unroll
  for (int i = 0; i < 4; ++i)
#pragma unroll
    for (int j = 0; j < 4; ++j)
      C[(size_t)(brow + tr * 4 + i) * NDIM + bcol + tc * 4 + j] = acc[i][j];
}

extern "C" void kernel_launch(void* const* d_in, const int* in_sizes, int n_in,
                              void* d_out, int out_size, void* d_ws, size_t ws_size,
                              hipStream_t stream) {
  const float* x = (const float*)d_in[0];
  const int* qw = (const int*)d_in[1];
  const void* sc = d_in[2];
  const void* zr = d_in[3];
  const float* lA = (const float*)d_in[4];
  const float* lB = (const float*)d_in[5];
  float* out = (float*)d_out;

  const size_t xb_bytes = (size_t)MDIM * KDIM * 2;
  const size_t weff_bytes = (size_t)NDIM * KDIM * 2;
  if (ws_size >= xb_bytes + weff_bytes) {
    u16* xb = (u16*)d_ws;
    u16* weff = xb + (size_t)MDIM * KDIM;
    qlora_prep<<<CONVB + WEFFB, 256, 0, stream>>>(x, (ushort4*)xb,
                                                  qw, sc, zr, lA, lB, (ushort2*)weff);
    dim3 grid((MDIM / 256) * (NDIM / 256));  // 512 blocks
    qlora_gemm_sp<<<grid, 512, 0, stream>>>(xb, weff, out);
  } else {
    dim3 grid(MDIM / 64, NDIM / 64);
    qlora_fallback<<<grid, 256, 0, stream>>>(x, qw, sc, zr, lA, lB, out);
  }
}